// Round 1
// baseline (72.182 us; speedup 1.0000x reference)
//
#include <hip/hip_runtime.h>
#include <math.h>

#define BB 8
#define TT 2048
#define VV 10
#define HH 5
#define CAP 32            // table capacity per head (expected ~14 hits)
#define THR 0.011         // residue window; winner provably within 7.63e-3

// Single fused kernel.
// Phase 0a: stage this batch's id row (8 KB) -> registers (global loads issued early).
// Phase 0b: wave w enumerates head-w candidate offsets by revolution index:
//           for n in [-326,377], o = rint(2*pi*n - off) is the unique integer
//           with minimal residue for that revolution; |r|<=THR hits (~14) are
//           placed in ascending deterministic order via ballot+popcount.
//           Residue is then recomputed with the exact fma sequence of the
//           previously-verified kernel; cos via degree-6 Taylor (<1 ulp at
//           |r|<=0.011). Table padded to a multiple of 8 with cr=-2 entries
//           (score ~ -9e13, can never beat any real candidate, all of which
//           are > 0; every (t,h) provably has a valid real candidate).
// Phase 0c: write staged ids -> LDS.
// Phase 1:  thread (wave w, lane r) scans head w's padded table for row t0+r,
//           fixed-trip unroll-8, all data from LDS. Same f64 scoring math as
//           the verified two-kernel version (argmax == one-hot softmax).
// Phase 2:  threads 0..63 run the f32 epilogue per row -> yL[64] (float2).
// Phase 3:  all 320 threads emit coalesced float2 stores (640 floats/block).
__global__ __launch_bounds__(320) void fused_rows(
    const int* __restrict__ ids,
    const float* __restrict__ o_w,
    const float* __restrict__ w1_abc,
    const float* __restrict__ w2_s,
    const float* __restrict__ embed_const,
    const float* __restrict__ decode_eps,
    const float* __restrict__ qk_scale,
    const float* __restrict__ rope_offsets,
    float* __restrict__ out)
{
    __shared__ int    idL[TT];        // 8 KB
    __shared__ int    oL[HH][CAP];
    __shared__ double crL[HH][CAP];
    __shared__ int    cntL[HH];       // padded counts (multiple of 8)
    __shared__ float  bdL[64][HH];
    __shared__ float2 yL[64];

    const int tid  = threadIdx.x;
    const int lane = tid & 63;
    const int w    = tid >> 6;        // wave id == head id, 0..4
    const int blk  = blockIdx.x;
    const int b    = blk >> 5;        // 32 blocks per batch row
    const int t0   = (blk & 31) << 6; // first t of this block
    const int* idb = ids + b * TT;

    // ---- phase 0a: issue id-staging loads (latency hidden under phase 0b) ----
    int stage[7];
    #pragma unroll
    for (int j = 0; j < 7; j++) {
        const int i = tid + j * 320;
        stage[j] = (i < TT) ? idb[i] : 0;
    }

    // ---- phase 0b: per-wave candidate table build ----
    {
        const double TWO_PI  = 6.283185307179586476925286766559;
        const double INV_2PI = 0.15915494309189533576888376337251;
        const double off = (double)rope_offsets[w];
        int cnt = 0;
        for (int c = 0; c < 11; c++) {                 // n in [-326, 377]
            const int n = c * 64 + lane - 326;
            const double on  = fma((double)n, TWO_PI, -off);
            const double od  = rint(on);               // candidate offset
            const double rr0 = od - on;
            const bool hit = (fabs(rr0) <= THR) && (fabs(od) <= 2047.0);
            const unsigned long long m = __ballot(hit);
            if (hit) {
                const int pos = cnt + __popcll(m & ((1ull << lane) - 1ull));
                // residue exactly as the verified kernel computed it
                const double a  = od + off;
                const double nn = rint(a * INV_2PI);
                const double r  = fma(-nn, TWO_PI, a);
                const double r2 = r * r;
                const double cr = 1.0 + r2 * (-0.5 + r2 * ((1.0 / 24.0)
                                            + r2 * (-1.0 / 720.0)));
                if (pos < CAP) { oL[w][pos] = (int)od; crL[w][pos] = cr; }
            }
            cnt += __popcll(m);
        }
        if (cnt > CAP) cnt = CAP;
        const int cnt_pad = (cnt + 7) & ~7;
        for (int i = cnt + lane; i < cnt_pad; i += 64) {
            oL[w][i] = 0;            // s=t, always in-range, unmasked
            crL[w][i] = -2.0;        // score ~ -9e13: can never win
        }
        if (lane == 0) cntL[w] = cnt_pad;
    }

    // ---- phase 0c: staged ids -> LDS ----
    #pragma unroll
    for (int j = 0; j < 7; j++) {
        const int i = tid + j * 320;
        if (i < TT) idL[i] = stage[j];
    }
    __syncthreads();

    // ---- phase 1: candidate scan (wave w = head w, lane = row) ----
    {
        const int t = t0 + lane;
        const double C    = (double)embed_const[0];
        const double quad = 0.5 * (double)decode_eps[0];
        const double qkd  = (double)qk_scale[0];

        const double dtd = (double)idL[t];
        const double x0t = C - quad * dtd * dtd;
        const double K = qkd * qkd * 0.70710678118654752440 * x0t;

        const int cnt_pad = cntL[w];
        double best = -1e300;
        float bdd = 0.0f;
        for (int i = 0; i < cnt_pad; i += 8) {
            #pragma unroll
            for (int u = 0; u < 8; u++) {
                const int o = oL[w][i + u];          // uniform LDS broadcast
                const double cr = crL[w][i + u];
                const int s = t + o;
                const bool valid = ((unsigned)s < (unsigned)TT);
                const double dd = (double)idL[valid ? s : 0];
                const double x0s = C - quad * dd * dd;
                double sc = K * x0s * cr;
                if (o > 0) sc -= 10000.0;            // causal mask (s>t)
                if (valid && sc > best) { best = sc; bdd = (float)dd; }
            }
        }
        bdL[lane][w] = bdd;
    }
    __syncthreads();

    // ---- phase 2: f32 epilogue per row (threads 0..63) ----
    if (tid < 64) {
        const float Cf    = embed_const[0];
        const float epsf  = decode_eps[0];
        const float quadf = 0.5f * epsf;
        const float dt_f  = (float)idL[t0 + tid];
        const float x0t_f = Cf - quadf * dt_f * dt_f;

        const float a0 = bdL[tid][0], a1 = bdL[tid][1], a2 = bdL[tid][2];
        const float a3 = bdL[tid][3], a4 = bdL[tid][4];
        const float upd0 = o_w[0] * a0 + o_w[1] * a1 + o_w[2] * a2;
        const float upd1 = o_w[3] * a0 + o_w[4] * a3 + o_w[5] * a4;

        const float x0 = x0t_f + upd0;
        const float x1 = dt_f + upd1;

        const float wa = w1_abc[0], wb = w1_abc[1], wc = w1_abc[2];
        const float h0 = fmaxf(wa * x0 + (Cf - 8.0f), 0.0f);
        const float h1 = fmaxf(wa * x0 + (Cf - 9.0f), 0.0f);
        const float h2 = fmaxf(wb * x0 + wc * x1 + (2.0f * Cf - 188.0f), 0.0f);
        const float h3 = fmaxf(wb * x0 + wc * x1 + (2.0f * Cf - 189.0f), 0.0f);

        const float s1 = w2_s[0], s10 = w2_s[1];
        const float x1f = x1 + s1 * h0 - s1 * h1 - s10 * h2 + s10 * h3;

        yL[tid] = make_float2(x0 * (1.0f / Cf), x1f * epsf);
    }
    __syncthreads();

    // ---- phase 3: coalesced float2 stores (all 320 threads) ----
    {
        const float Cf    = embed_const[0];
        const float quadf = 0.5f * decode_eps[0];
        const int idx = tid * 2;               // 0..638, even => never straddles a row
        const int rl  = idx / 10;              // local row
        const int v0  = idx - rl * 10;         // even digit
        const float2 y = yL[rl];
        const float fv0 = (float)v0;
        const float fv1 = (float)(v0 + 1);
        const float e0 = Cf - quadf * fv0 * fv0;
        const float e1 = Cf - quadf * fv1 * fv1;
        float2 o2;
        o2.x = y.x * e0 + y.y * fv0;
        o2.y = y.x * e1 + y.y * fv1;
        *reinterpret_cast<float2*>(out + (size_t)blk * 640 + idx) = o2;
    }
}

extern "C" void kernel_launch(void* const* d_in, const int* in_sizes, int n_in,
                              void* d_out, int out_size, void* d_ws, size_t ws_size,
                              hipStream_t stream) {
    (void)in_sizes; (void)n_in; (void)ws_size; (void)out_size; (void)d_ws;
    const int*   ids = (const int*)  d_in[0];
    const float* o_w = (const float*)d_in[1];
    const float* w1  = (const float*)d_in[2];
    const float* w2  = (const float*)d_in[3];
    const float* Cc  = (const float*)d_in[4];
    const float* ee  = (const float*)d_in[5];
    const float* qq  = (const float*)d_in[6];
    const float* ro  = (const float*)d_in[7];
    float* out = (float*)d_out;

    hipLaunchKernelGGL(fused_rows, dim3(BB * TT / 64), dim3(320), 0, stream,
                       ids, o_w, w1, w2, Cc, ee, qq, ro, out);
}